// Round 1
// baseline (530.242 us; speedup 1.0000x reference)
//
#include <hip/hip_runtime.h>

#define BN_EPS 1e-5f

// ---------------- CSR build ----------------

__global__ void k_init_deg(int* deg, int N) {
    int i = blockIdx.x * blockDim.x + threadIdx.x;
    if (i < N) deg[i] = 1;  // self-loop
}

__global__ void k_hist(const int* __restrict__ dst, int* deg, int E) {
    int e = blockIdx.x * blockDim.x + threadIdx.x;
    if (e < E) atomicAdd(&deg[dst[e]], 1);
}

__global__ void k_dinv(const int* __restrict__ deg, float* __restrict__ dinv, int N) {
    int i = blockIdx.x * blockDim.x + threadIdx.x;
    if (i < N) dinv[i] = rsqrtf((float)deg[i]);  // deg >= 1 always
}

// single-block exclusive scan of (deg[i]-1) -> row_ptr[0..N]
__global__ void k_scan(const int* __restrict__ deg, int* __restrict__ row_ptr, int N) {
    __shared__ int sums[1024];
    int tid = threadIdx.x;
    int chunk = (N + 1023) >> 10;
    int s0 = tid * chunk;
    int s1 = min(s0 + chunk, N);
    int loc = 0;
    for (int i = s0; i < s1; ++i) loc += deg[i] - 1;
    sums[tid] = loc;
    __syncthreads();
    for (int off = 1; off < 1024; off <<= 1) {
        int t = (tid >= off) ? sums[tid - off] : 0;
        __syncthreads();
        sums[tid] += t;
        __syncthreads();
    }
    int run = sums[tid] - loc;  // exclusive prefix
    for (int i = s0; i < s1; ++i) { row_ptr[i] = run; run += deg[i] - 1; }
    if (tid == 1023) row_ptr[N] = sums[1023];
}

__global__ void k_cursor(const int* __restrict__ row_ptr, int* __restrict__ cursor, int N) {
    int i = blockIdx.x * blockDim.x + threadIdx.x;
    if (i < N) cursor[i] = row_ptr[i];
}

__global__ void k_scatter(const int* __restrict__ src, const int* __restrict__ dst,
                          int* cursor, int* __restrict__ col, int E) {
    int e = blockIdx.x * blockDim.x + threadIdx.x;
    if (e < E) {
        int d = dst[e];
        int p = atomicAdd(&cursor[d], 1);
        col[p] = src[e];
    }
}

// ---------------- GEMM with dinv-prescale epilogue ----------------
// HS[row][f] = dinv[row] * (X @ W)[row][f]
// 256 threads, 64-row x FOUT-col tile. Thread (tr=tid/16, tc=tid%16) does 4x4.
template <int K, int FOUT>
__launch_bounds__(256)
__global__ void k_gemm_scale(const float* __restrict__ X, const float* __restrict__ W,
                             const float* __restrict__ dinv, float* __restrict__ HS, int N) {
    __shared__ float xs[K][65];   // +1 pad: conflict-free write & broadcast read
    __shared__ float wl[K][FOUT];
    int tid = threadIdx.x;
    int row0 = blockIdx.x * 64;

    for (int idx = tid; idx < K * FOUT; idx += 256)
        wl[idx / FOUT][idx % FOUT] = W[idx];
    for (int idx = tid; idx < 64 * K; idx += 256) {
        int r = idx / K, k = idx % K;   // K is pow2 template const
        int row = row0 + r;
        xs[k][r] = (row < N) ? X[row * K + k] : 0.0f;
    }
    __syncthreads();

    int tc = tid & 15, tr = tid >> 4;
    if (4 * tc < FOUT) {
        float acc[4][4] = {};
#pragma unroll 8
        for (int k = 0; k < K; ++k) {
            float a0 = xs[k][4 * tr + 0];
            float a1 = xs[k][4 * tr + 1];
            float a2 = xs[k][4 * tr + 2];
            float a3 = xs[k][4 * tr + 3];
            const float4 w = *reinterpret_cast<const float4*>(&wl[k][4 * tc]);
            acc[0][0] += a0 * w.x; acc[0][1] += a0 * w.y; acc[0][2] += a0 * w.z; acc[0][3] += a0 * w.w;
            acc[1][0] += a1 * w.x; acc[1][1] += a1 * w.y; acc[1][2] += a1 * w.z; acc[1][3] += a1 * w.w;
            acc[2][0] += a2 * w.x; acc[2][1] += a2 * w.y; acc[2][2] += a2 * w.z; acc[2][3] += a2 * w.w;
            acc[3][0] += a3 * w.x; acc[3][1] += a3 * w.y; acc[3][2] += a3 * w.z; acc[3][3] += a3 * w.w;
        }
#pragma unroll
        for (int i = 0; i < 4; ++i) {
            int row = row0 + 4 * tr + i;
            if (row < N) {
                float dv = dinv[row];
                float4 o;
                o.x = dv * acc[i][0]; o.y = dv * acc[i][1];
                o.z = dv * acc[i][2]; o.w = dv * acc[i][3];
                *reinterpret_cast<float4*>(&HS[row * FOUT + 4 * tc]) = o;
            }
        }
    }
}

// ---------------- Aggregation: out[d] = post(dinv[d]*(hs[d]+sum_in hs[s]) + b) ----------------
// one wave per node, lane = feature
template <int FOUT, bool BN>
__launch_bounds__(256)
__global__ void k_agg(const float* __restrict__ hs, const int* __restrict__ col,
                      const int* __restrict__ row_ptr, const float* __restrict__ dinv,
                      const float* __restrict__ b, const float* __restrict__ g,
                      const float* __restrict__ be, const float* __restrict__ m,
                      const float* __restrict__ v, float* __restrict__ out, int N) {
    int gtid = blockIdx.x * blockDim.x + threadIdx.x;
    int wave = gtid >> 6;
    int lane = gtid & 63;
    int nwaves = (gridDim.x * blockDim.x) >> 6;
    bool active = lane < FOUT;

    float bias = 0.f, sf = 0.f, tf = 0.f;
    if (active) {
        bias = b[lane];
        if (BN) {
            sf = g[lane] * rsqrtf(v[lane] + BN_EPS);
            tf = be[lane] - m[lane] * sf;
        }
    }

    for (int node = wave; node < N; node += nwaves) {
        int beg = row_ptr[node], end = row_ptr[node + 1];
        float a0 = 0.f, a1 = 0.f, a2 = 0.f, a3 = 0.f;
        if (active) a0 = hs[node * FOUT + lane];
        int e = beg;
        for (; e + 4 <= end; e += 4) {
            int s0 = col[e], s1 = col[e + 1], s2 = col[e + 2], s3 = col[e + 3];
            if (active) {
                a0 += hs[s0 * FOUT + lane];
                a1 += hs[s1 * FOUT + lane];
                a2 += hs[s2 * FOUT + lane];
                a3 += hs[s3 * FOUT + lane];
            }
        }
        for (; e < end; ++e) {
            int s = col[e];
            if (active) a0 += hs[s * FOUT + lane];
        }
        if (active) {
            float o = dinv[node] * ((a0 + a1) + (a2 + a3)) + bias;
            if (BN) o = fmaxf(o * sf + tf, 0.0f);
            out[node * FOUT + lane] = o;
        }
    }
}

// ---------------- launch ----------------

extern "C" void kernel_launch(void* const* d_in, const int* in_sizes, int n_in,
                              void* d_out, int out_size, void* d_ws, size_t ws_size,
                              hipStream_t stream) {
    const float* x   = (const float*)d_in[0];
    const int*   ei  = (const int*)d_in[1];
    const float* W1  = (const float*)d_in[2];
    const float* b1  = (const float*)d_in[3];
    const float* g1  = (const float*)d_in[4];
    const float* be1 = (const float*)d_in[5];
    const float* m1  = (const float*)d_in[6];
    const float* v1  = (const float*)d_in[7];
    const float* W2  = (const float*)d_in[8];
    const float* b2  = (const float*)d_in[9];
    const float* g2  = (const float*)d_in[10];
    const float* be2 = (const float*)d_in[11];
    const float* m2  = (const float*)d_in[12];
    const float* v2  = (const float*)d_in[13];
    const float* W3  = (const float*)d_in[14];
    const float* b3  = (const float*)d_in[15];

    const int FIN = 128, H = 64, C = 40;
    int N = in_sizes[0] / FIN;       // 50000
    int E = in_sizes[1] / 2;         // 1600000
    const int* src = ei;
    const int* dst = ei + E;

    // workspace carve (256B aligned)
    char* ws = (char*)d_ws;
    size_t off = 0;
    auto carve = [&](size_t bytes) -> void* {
        void* p = ws + off;
        off += (bytes + 255) & ~(size_t)255;
        return p;
    };
    int*   deg     = (int*)carve((size_t)N * 4);
    float* dinv    = (float*)carve((size_t)N * 4);
    int*   row_ptr = (int*)carve((size_t)(N + 1) * 4);
    int*   cursor  = (int*)carve((size_t)N * 4);
    int*   col     = (int*)carve((size_t)E * 4);
    float* hs      = (float*)carve((size_t)N * H * 4);
    float* y       = (float*)carve((size_t)N * H * 4);
    (void)ws_size; (void)n_in; (void)out_size;

    int nb = (N + 255) / 256;
    int eb = (E + 255) / 256;

    k_init_deg<<<nb, 256, 0, stream>>>(deg, N);
    k_hist<<<eb, 256, 0, stream>>>(dst, deg, E);
    k_dinv<<<nb, 256, 0, stream>>>(deg, dinv, N);
    k_scan<<<1, 1024, 0, stream>>>(deg, row_ptr, N);
    k_cursor<<<nb, 256, 0, stream>>>(row_ptr, cursor, N);
    k_scatter<<<eb, 256, 0, stream>>>(src, dst, cursor, col, E);

    int gb = (N + 63) / 64;
    // layer 1
    k_gemm_scale<128, 64><<<gb, 256, 0, stream>>>(x, W1, dinv, hs, N);
    k_agg<64, true><<<4096, 256, 0, stream>>>(hs, col, row_ptr, dinv, b1, g1, be1, m1, v1, y, N);
    // layer 2
    k_gemm_scale<64, 64><<<gb, 256, 0, stream>>>(y, W2, dinv, hs, N);
    k_agg<64, true><<<4096, 256, 0, stream>>>(hs, col, row_ptr, dinv, b2, g2, be2, m2, v2, y, N);
    // layer 3
    k_gemm_scale<64, 40><<<gb, 256, 0, stream>>>(y, W3, dinv, hs, N);
    k_agg<40, false><<<4096, 256, 0, stream>>>(hs, col, row_ptr, dinv, b3, nullptr, nullptr, nullptr, nullptr,
                                               (float*)d_out, N);
}

// Round 2
// 514.938 us; speedup vs baseline: 1.0297x; 1.0297x over previous
//
#include <hip/hip_runtime.h>
#include <hip/hip_fp16.h>

#define BN_EPS 1e-5f

// ---------------- CSR build ----------------

__global__ void k_init_deg(int* deg, int N) {
    int i = blockIdx.x * blockDim.x + threadIdx.x;
    if (i < N) deg[i] = 1;  // self-loop
}

__global__ void k_hist(const int* __restrict__ dst, int* deg, int E) {
    int e = blockIdx.x * blockDim.x + threadIdx.x;
    if (e < E) atomicAdd(&deg[dst[e]], 1);
}

// single-block scan: row_ptr[0..N] (excl. self-loops), plus cursor copy and dinv
__global__ void k_scan(const int* __restrict__ deg, int* __restrict__ row_ptr,
                       int* __restrict__ cursor, float* __restrict__ dinv, int N) {
    __shared__ int sums[1024];
    int tid = threadIdx.x;
    int chunk = (N + 1023) >> 10;
    int s0 = tid * chunk;
    int s1 = min(s0 + chunk, N);
    int loc = 0;
    for (int i = s0; i < s1; ++i) loc += deg[i] - 1;
    sums[tid] = loc;
    __syncthreads();
    for (int off = 1; off < 1024; off <<= 1) {
        int t = (tid >= off) ? sums[tid - off] : 0;
        __syncthreads();
        sums[tid] += t;
        __syncthreads();
    }
    int run = sums[tid] - loc;  // exclusive prefix
    for (int i = s0; i < s1; ++i) {
        int d = deg[i];
        row_ptr[i] = run;
        cursor[i] = run;
        dinv[i] = rsqrtf((float)d);
        run += d - 1;
    }
    if (tid == 1023) row_ptr[N] = sums[1023];
}

__global__ void k_scatter(const int* __restrict__ src, const int* __restrict__ dst,
                          int* cursor, unsigned short* __restrict__ col, int E) {
    int e = blockIdx.x * blockDim.x + threadIdx.x;
    if (e < E) {
        int d = dst[e];
        int p = atomicAdd(&cursor[d], 1);
        col[p] = (unsigned short)src[e];
    }
}

// ---------------- GEMM with dinv-prescale epilogue, fp16 output ----------------
// HS[row][f] = fp16( dinv[row] * (X @ W)[row][f] )
template <int K, int FOUT>
__launch_bounds__(256)
__global__ void k_gemm_scale(const float* __restrict__ X, const float* __restrict__ W,
                             const float* __restrict__ dinv, __half* __restrict__ HS, int N) {
    __shared__ float xs[K][65];   // +1 pad
    __shared__ float wl[K][FOUT];
    int tid = threadIdx.x;
    int row0 = blockIdx.x * 64;

    for (int idx = tid; idx < K * FOUT; idx += 256)
        wl[idx / FOUT][idx % FOUT] = W[idx];
    for (int idx = tid; idx < 64 * K; idx += 256) {
        int r = idx / K, k = idx % K;
        int row = row0 + r;
        xs[k][r] = (row < N) ? X[row * K + k] : 0.0f;
    }
    __syncthreads();

    int tc = tid & 15, tr = tid >> 4;
    if (4 * tc < FOUT) {
        float acc[4][4] = {};
#pragma unroll 8
        for (int k = 0; k < K; ++k) {
            float a0 = xs[k][4 * tr + 0];
            float a1 = xs[k][4 * tr + 1];
            float a2 = xs[k][4 * tr + 2];
            float a3 = xs[k][4 * tr + 3];
            const float4 w = *reinterpret_cast<const float4*>(&wl[k][4 * tc]);
            acc[0][0] += a0 * w.x; acc[0][1] += a0 * w.y; acc[0][2] += a0 * w.z; acc[0][3] += a0 * w.w;
            acc[1][0] += a1 * w.x; acc[1][1] += a1 * w.y; acc[1][2] += a1 * w.z; acc[1][3] += a1 * w.w;
            acc[2][0] += a2 * w.x; acc[2][1] += a2 * w.y; acc[2][2] += a2 * w.z; acc[2][3] += a2 * w.w;
            acc[3][0] += a3 * w.x; acc[3][1] += a3 * w.y; acc[3][2] += a3 * w.z; acc[3][3] += a3 * w.w;
        }
#pragma unroll
        for (int i = 0; i < 4; ++i) {
            int row = row0 + 4 * tr + i;
            if (row < N) {
                float dv = dinv[row];
                __half2 h0 = __floats2half2_rn(dv * acc[i][0], dv * acc[i][1]);
                __half2 h1 = __floats2half2_rn(dv * acc[i][2], dv * acc[i][3]);
                __half2* p = reinterpret_cast<__half2*>(&HS[row * FOUT + 4 * tc]);
                p[0] = h0; p[1] = h1;
            }
        }
    }
}

// ---------------- Aggregation ----------------
// one wave per node; lanes 0-31 / 32-63 process alternating edges (stride 2),
// each lane holds one half2 (two features); combine halves with shfl_xor(32).
template <int FOUT, bool BN>
__launch_bounds__(256)
__global__ void k_agg(const __half2* __restrict__ hs2, const unsigned short* __restrict__ col,
                      const int* __restrict__ row_ptr, const float* __restrict__ dinv,
                      const float* __restrict__ b, const float* __restrict__ g,
                      const float* __restrict__ be, const float* __restrict__ m,
                      const float* __restrict__ v, float* __restrict__ out, int N) {
    constexpr int NP = FOUT / 2;  // half2 per row
    int gtid = blockIdx.x * blockDim.x + threadIdx.x;
    int wave = gtid >> 6;
    int lane = gtid & 63;
    int half = lane >> 5;
    int l = lane & 31;
    int nwaves = (gridDim.x * blockDim.x) >> 6;
    bool active = l < NP;

    float b0 = 0.f, b1 = 0.f, s0f = 0.f, s1f = 0.f, t0f = 0.f, t1f = 0.f;
    if (active) {
        b0 = b[2 * l]; b1 = b[2 * l + 1];
        if (BN) {
            s0f = g[2 * l] * rsqrtf(v[2 * l] + BN_EPS);
            s1f = g[2 * l + 1] * rsqrtf(v[2 * l + 1] + BN_EPS);
            t0f = be[2 * l] - m[2 * l] * s0f;
            t1f = be[2 * l + 1] - m[2 * l + 1] * s1f;
        }
    }

    float2* out2 = reinterpret_cast<float2*>(out);

    for (int node = wave; node < N; node += nwaves) {
        int beg = row_ptr[node], end = row_ptr[node + 1];
        float ax = 0.f, ay = 0.f, bx = 0.f, by = 0.f;
        float cx = 0.f, cy = 0.f, dx = 0.f, dy = 0.f;
        if (active && half == 0) {
            float2 t = __half22float2(hs2[node * NP + l]);
            ax = t.x; ay = t.y;
        }
        int e = beg + half;
        for (; e + 6 < end; e += 8) {
            int i0 = col[e], i1 = col[e + 2], i2 = col[e + 4], i3 = col[e + 6];
            if (active) {
                float2 t0 = __half22float2(hs2[i0 * NP + l]);
                float2 t1 = __half22float2(hs2[i1 * NP + l]);
                float2 t2 = __half22float2(hs2[i2 * NP + l]);
                float2 t3 = __half22float2(hs2[i3 * NP + l]);
                ax += t0.x; ay += t0.y;
                bx += t1.x; by += t1.y;
                cx += t2.x; cy += t2.y;
                dx += t3.x; dy += t3.y;
            }
        }
        for (; e < end; e += 2) {
            int i0 = col[e];
            if (active) {
                float2 t0 = __half22float2(hs2[i0 * NP + l]);
                ax += t0.x; ay += t0.y;
            }
        }
        float sx = (ax + bx) + (cx + dx);
        float sy = (ay + by) + (cy + dy);
        sx += __shfl_xor(sx, 32);
        sy += __shfl_xor(sy, 32);
        if (active && half == 0) {
            float dv = dinv[node];
            float o0 = dv * sx + b0;
            float o1 = dv * sy + b1;
            if (BN) {
                o0 = fmaxf(o0 * s0f + t0f, 0.0f);
                o1 = fmaxf(o1 * s1f + t1f, 0.0f);
            }
            out2[node * NP + l] = make_float2(o0, o1);
        }
    }
}

// ---------------- launch ----------------

extern "C" void kernel_launch(void* const* d_in, const int* in_sizes, int n_in,
                              void* d_out, int out_size, void* d_ws, size_t ws_size,
                              hipStream_t stream) {
    const float* x   = (const float*)d_in[0];
    const int*   ei  = (const int*)d_in[1];
    const float* W1  = (const float*)d_in[2];
    const float* b1  = (const float*)d_in[3];
    const float* g1  = (const float*)d_in[4];
    const float* be1 = (const float*)d_in[5];
    const float* m1  = (const float*)d_in[6];
    const float* v1  = (const float*)d_in[7];
    const float* W2  = (const float*)d_in[8];
    const float* b2  = (const float*)d_in[9];
    const float* g2  = (const float*)d_in[10];
    const float* be2 = (const float*)d_in[11];
    const float* m2  = (const float*)d_in[12];
    const float* v2  = (const float*)d_in[13];
    const float* W3  = (const float*)d_in[14];
    const float* b3  = (const float*)d_in[15];

    const int FIN = 128, H = 64;
    int N = in_sizes[0] / FIN;       // 50000
    int E = in_sizes[1] / 2;         // 1600000
    const int* src = ei;
    const int* dst = ei + E;

    char* ws = (char*)d_ws;
    size_t off = 0;
    auto carve = [&](size_t bytes) -> void* {
        void* p = ws + off;
        off += (bytes + 255) & ~(size_t)255;
        return p;
    };
    int*    deg     = (int*)carve((size_t)N * 4);
    float*  dinv    = (float*)carve((size_t)N * 4);
    int*    row_ptr = (int*)carve((size_t)(N + 1) * 4);
    int*    cursor  = (int*)carve((size_t)N * 4);
    unsigned short* col = (unsigned short*)carve((size_t)E * 2);
    __half* hs      = (__half*)carve((size_t)N * H * 2);
    float*  y       = (float*)carve((size_t)N * H * 4);
    (void)ws_size; (void)n_in; (void)out_size;

    int nb = (N + 255) / 256;
    int eb = (E + 255) / 256;

    k_init_deg<<<nb, 256, 0, stream>>>(deg, N);
    k_hist<<<eb, 256, 0, stream>>>(dst, deg, E);
    k_scan<<<1, 1024, 0, stream>>>(deg, row_ptr, cursor, dinv, N);
    k_scatter<<<eb, 256, 0, stream>>>(src, dst, cursor, col, E);

    int gb = (N + 63) / 64;
    const __half2* hs2 = (const __half2*)hs;
    // layer 1
    k_gemm_scale<128, 64><<<gb, 256, 0, stream>>>(x, W1, dinv, hs, N);
    k_agg<64, true><<<4096, 256, 0, stream>>>(hs2, col, row_ptr, dinv, b1, g1, be1, m1, v1, y, N);
    // layer 2
    k_gemm_scale<64, 64><<<gb, 256, 0, stream>>>(y, W2, dinv, hs, N);
    k_agg<64, true><<<4096, 256, 0, stream>>>(hs2, col, row_ptr, dinv, b2, g2, be2, m2, v2, y, N);
    // layer 3
    k_gemm_scale<64, 40><<<gb, 256, 0, stream>>>(y, W3, dinv, hs, N);
    k_agg<40, false><<<4096, 256, 0, stream>>>(hs2, col, row_ptr, dinv, b3, nullptr, nullptr, nullptr, nullptr,
                                               (float*)d_out, N);
}

// Round 3
// 390.252 us; speedup vs baseline: 1.3587x; 1.3195x over previous
//
#include <hip/hip_runtime.h>
#include <hip/hip_fp16.h>

#define BN_EPS 1e-5f

// ---------------- CSR build ----------------

__global__ void k_init_deg(int* deg, int N) {
    int i = blockIdx.x * blockDim.x + threadIdx.x;
    if (i < N) deg[i] = 1;  // self-loop
}

__global__ void k_hist(const int* __restrict__ dst, int* deg, int E) {
    int e = blockIdx.x * blockDim.x + threadIdx.x;
    if (e < E) atomicAdd(&deg[dst[e]], 1);
}

// ---- 3-phase multi-block exclusive scan of (deg[i]-1) ----
// phase A: per-block (1024 elems) partial sums
__global__ void k_scan_partial(const int* __restrict__ deg, int* __restrict__ bsum, int N) {
    int base = blockIdx.x * 1024 + threadIdx.x * 4;
    int s = 0;
#pragma unroll
    for (int j = 0; j < 4; ++j) {
        int idx = base + j;
        if (idx < N) s += deg[idx] - 1;
    }
    for (int off = 1; off < 64; off <<= 1) s += __shfl_xor(s, off);
    __shared__ int ws[4];
    int lane = threadIdx.x & 63, w = threadIdx.x >> 6;
    if (lane == 0) ws[w] = s;
    __syncthreads();
    if (threadIdx.x == 0) bsum[blockIdx.x] = ws[0] + ws[1] + ws[2] + ws[3];
}

// phase B: scan the block sums (nb <= 1024)
__global__ void k_scan_blocks(const int* __restrict__ bsum, int* __restrict__ bsumx, int nb) {
    __shared__ int sums[1024];
    int tid = threadIdx.x;
    int v = (tid < nb) ? bsum[tid] : 0;
    sums[tid] = v;
    __syncthreads();
    for (int off = 1; off < 1024; off <<= 1) {
        int t = (tid >= off) ? sums[tid - off] : 0;
        __syncthreads();
        sums[tid] += t;
        __syncthreads();
    }
    if (tid < nb) bsumx[tid] = sums[tid] - v;  // exclusive
}

// phase C: final scan + emit row_ptr, cursor, dinv, row_ptr[N]
__global__ void k_scan_final(const int* __restrict__ deg, const int* __restrict__ bsumx,
                             int* __restrict__ row_ptr, int* __restrict__ cursor,
                             float* __restrict__ dinv, int N) {
    int tid = threadIdx.x;
    int base = blockIdx.x * 1024 + tid * 4;
    int d[4], v[4];
#pragma unroll
    for (int j = 0; j < 4; ++j) {
        int idx = base + j;
        d[j] = (idx < N) ? deg[idx] : 1;
        v[j] = d[j] - 1;
    }
    int tsum = v[0] + v[1] + v[2] + v[3];
    int lane = tid & 63, w = tid >> 6;
    int x = tsum;
    for (int off = 1; off < 64; off <<= 1) {
        int n = __shfl_up(x, off);
        if (lane >= off) x += n;
    }
    __shared__ int wsum[4];
    if (lane == 63) wsum[w] = x;
    __syncthreads();
    int woff = 0;
#pragma unroll
    for (int i = 0; i < 4; ++i)
        if (i < w) woff += wsum[i];
    int run = bsumx[blockIdx.x] + woff + (x - tsum);  // exclusive prefix
#pragma unroll
    for (int j = 0; j < 4; ++j) {
        int idx = base + j;
        if (idx < N) {
            row_ptr[idx] = run;
            cursor[idx] = run;
            dinv[idx] = rsqrtf((float)d[j]);
            run += v[j];
            if (idx == N - 1) row_ptr[N] = run;
        }
    }
}

__global__ void k_scatter(const int* __restrict__ src, const int* __restrict__ dst,
                          int* cursor, unsigned short* __restrict__ col, int E) {
    int e = blockIdx.x * blockDim.x + threadIdx.x;
    if (e < E) {
        int d = dst[e];
        int p = atomicAdd(&cursor[d], 1);
        col[p] = (unsigned short)src[e];
    }
}

// ---------------- GEMM with dinv-prescale epilogue, fp16 output ----------------
template <int K, int FOUT>
__launch_bounds__(256)
__global__ void k_gemm_scale(const float* __restrict__ X, const float* __restrict__ W,
                             const float* __restrict__ dinv, __half* __restrict__ HS, int N) {
    __shared__ float xs[K][65];
    __shared__ float wl[K][FOUT];
    int tid = threadIdx.x;
    int row0 = blockIdx.x * 64;

    for (int idx = tid; idx < K * FOUT; idx += 256)
        wl[idx / FOUT][idx % FOUT] = W[idx];
    for (int idx = tid; idx < 64 * K; idx += 256) {
        int r = idx / K, k = idx % K;
        int row = row0 + r;
        xs[k][r] = (row < N) ? X[row * K + k] : 0.0f;
    }
    __syncthreads();

    int tc = tid & 15, tr = tid >> 4;
    if (4 * tc < FOUT) {
        float acc[4][4] = {};
#pragma unroll 8
        for (int k = 0; k < K; ++k) {
            float a0 = xs[k][4 * tr + 0];
            float a1 = xs[k][4 * tr + 1];
            float a2 = xs[k][4 * tr + 2];
            float a3 = xs[k][4 * tr + 3];
            const float4 w = *reinterpret_cast<const float4*>(&wl[k][4 * tc]);
            acc[0][0] += a0 * w.x; acc[0][1] += a0 * w.y; acc[0][2] += a0 * w.z; acc[0][3] += a0 * w.w;
            acc[1][0] += a1 * w.x; acc[1][1] += a1 * w.y; acc[1][2] += a1 * w.z; acc[1][3] += a1 * w.w;
            acc[2][0] += a2 * w.x; acc[2][1] += a2 * w.y; acc[2][2] += a2 * w.z; acc[2][3] += a2 * w.w;
            acc[3][0] += a3 * w.x; acc[3][1] += a3 * w.y; acc[3][2] += a3 * w.z; acc[3][3] += a3 * w.w;
        }
#pragma unroll
        for (int i = 0; i < 4; ++i) {
            int row = row0 + 4 * tr + i;
            if (row < N) {
                float dv = dinv[row];
                __half2 h0 = __floats2half2_rn(dv * acc[i][0], dv * acc[i][1]);
                __half2 h1 = __floats2half2_rn(dv * acc[i][2], dv * acc[i][3]);
                __half2* p = reinterpret_cast<__half2*>(&HS[row * FOUT + 4 * tc]);
                p[0] = h0; p[1] = h1;
            }
        }
    }
}

// ---------------- Aggregation ----------------
template <int FOUT, bool BN>
__launch_bounds__(256)
__global__ void k_agg(const __half2* __restrict__ hs2, const unsigned short* __restrict__ col,
                      const int* __restrict__ row_ptr, const float* __restrict__ dinv,
                      const float* __restrict__ b, const float* __restrict__ g,
                      const float* __restrict__ be, const float* __restrict__ m,
                      const float* __restrict__ v, float* __restrict__ out, int N) {
    constexpr int NP = FOUT / 2;  // half2 per row
    int gtid = blockIdx.x * blockDim.x + threadIdx.x;
    int wave = gtid >> 6;
    int lane = gtid & 63;
    int half = lane >> 5;
    int l = lane & 31;
    int nwaves = (gridDim.x * blockDim.x) >> 6;
    bool active = l < NP;

    float b0 = 0.f, b1 = 0.f, s0f = 0.f, s1f = 0.f, t0f = 0.f, t1f = 0.f;
    if (active) {
        b0 = b[2 * l]; b1 = b[2 * l + 1];
        if (BN) {
            s0f = g[2 * l] * rsqrtf(v[2 * l] + BN_EPS);
            s1f = g[2 * l + 1] * rsqrtf(v[2 * l + 1] + BN_EPS);
            t0f = be[2 * l] - m[2 * l] * s0f;
            t1f = be[2 * l + 1] - m[2 * l + 1] * s1f;
        }
    }

    float2* out2 = reinterpret_cast<float2*>(out);

    for (int node = wave; node < N; node += nwaves) {
        int beg = row_ptr[node], end = row_ptr[node + 1];
        float ax = 0.f, ay = 0.f, bx = 0.f, by = 0.f;
        float cx = 0.f, cy = 0.f, dx = 0.f, dy = 0.f;
        if (active && half == 0) {
            float2 t = __half22float2(hs2[node * NP + l]);
            ax = t.x; ay = t.y;
        }
        int e = beg + half;
        for (; e + 6 < end; e += 8) {
            int i0 = col[e], i1 = col[e + 2], i2 = col[e + 4], i3 = col[e + 6];
            if (active) {
                float2 t0 = __half22float2(hs2[i0 * NP + l]);
                float2 t1 = __half22float2(hs2[i1 * NP + l]);
                float2 t2 = __half22float2(hs2[i2 * NP + l]);
                float2 t3 = __half22float2(hs2[i3 * NP + l]);
                ax += t0.x; ay += t0.y;
                bx += t1.x; by += t1.y;
                cx += t2.x; cy += t2.y;
                dx += t3.x; dy += t3.y;
            }
        }
        for (; e < end; e += 2) {
            int i0 = col[e];
            if (active) {
                float2 t0 = __half22float2(hs2[i0 * NP + l]);
                ax += t0.x; ay += t0.y;
            }
        }
        float sx = (ax + bx) + (cx + dx);
        float sy = (ay + by) + (cy + dy);
        sx += __shfl_xor(sx, 32);
        sy += __shfl_xor(sy, 32);
        if (active && half == 0) {
            float dv = dinv[node];
            float o0 = dv * sx + b0;
            float o1 = dv * sy + b1;
            if (BN) {
                o0 = fmaxf(o0 * s0f + t0f, 0.0f);
                o1 = fmaxf(o1 * s1f + t1f, 0.0f);
            }
            out2[node * NP + l] = make_float2(o0, o1);
        }
    }
}

// ---------------- launch ----------------

extern "C" void kernel_launch(void* const* d_in, const int* in_sizes, int n_in,
                              void* d_out, int out_size, void* d_ws, size_t ws_size,
                              hipStream_t stream) {
    const float* x   = (const float*)d_in[0];
    const int*   ei  = (const int*)d_in[1];
    const float* W1  = (const float*)d_in[2];
    const float* b1  = (const float*)d_in[3];
    const float* g1  = (const float*)d_in[4];
    const float* be1 = (const float*)d_in[5];
    const float* m1  = (const float*)d_in[6];
    const float* v1  = (const float*)d_in[7];
    const float* W2  = (const float*)d_in[8];
    const float* b2  = (const float*)d_in[9];
    const float* g2  = (const float*)d_in[10];
    const float* be2 = (const float*)d_in[11];
    const float* m2  = (const float*)d_in[12];
    const float* v2  = (const float*)d_in[13];
    const float* W3  = (const float*)d_in[14];
    const float* b3  = (const float*)d_in[15];

    const int FIN = 128, H = 64;
    int N = in_sizes[0] / FIN;       // 50000
    int E = in_sizes[1] / 2;         // 1600000
    const int* src = ei;
    const int* dst = ei + E;

    char* ws = (char*)d_ws;
    size_t off = 0;
    auto carve = [&](size_t bytes) -> void* {
        void* p = ws + off;
        off += (bytes + 255) & ~(size_t)255;
        return p;
    };
    int*    deg     = (int*)carve((size_t)N * 4);
    float*  dinv    = (float*)carve((size_t)N * 4);
    int*    row_ptr = (int*)carve((size_t)(N + 1) * 4);
    int*    cursor  = (int*)carve((size_t)N * 4);
    unsigned short* col = (unsigned short*)carve((size_t)E * 2);
    __half* hs      = (__half*)carve((size_t)N * H * 2);
    float*  y       = (float*)carve((size_t)N * H * 4);
    int*    bsum    = (int*)carve(2048 * 4);
    int*    bsumx   = (int*)carve(2048 * 4);
    (void)ws_size; (void)n_in; (void)out_size;

    int nb = (N + 255) / 256;
    int eb = (E + 255) / 256;
    int sb = (N + 1023) / 1024;  // scan blocks (1024 elems each)

    k_init_deg<<<nb, 256, 0, stream>>>(deg, N);
    k_hist<<<eb, 256, 0, stream>>>(dst, deg, E);
    k_scan_partial<<<sb, 256, 0, stream>>>(deg, bsum, N);
    k_scan_blocks<<<1, 1024, 0, stream>>>(bsum, bsumx, sb);
    k_scan_final<<<sb, 256, 0, stream>>>(deg, bsumx, row_ptr, cursor, dinv, N);
    k_scatter<<<eb, 256, 0, stream>>>(src, dst, cursor, col, E);

    int gb = (N + 63) / 64;
    const __half2* hs2 = (const __half2*)hs;
    // layer 1
    k_gemm_scale<128, 64><<<gb, 256, 0, stream>>>(x, W1, dinv, hs, N);
    k_agg<64, true><<<4096, 256, 0, stream>>>(hs2, col, row_ptr, dinv, b1, g1, be1, m1, v1, y, N);
    // layer 2
    k_gemm_scale<64, 64><<<gb, 256, 0, stream>>>(y, W2, dinv, hs, N);
    k_agg<64, true><<<4096, 256, 0, stream>>>(hs2, col, row_ptr, dinv, b2, g2, be2, m2, v2, y, N);
    // layer 3
    k_gemm_scale<64, 40><<<gb, 256, 0, stream>>>(y, W3, dinv, hs, N);
    k_agg<40, false><<<4096, 256, 0, stream>>>(hs2, col, row_ptr, dinv, b3, nullptr, nullptr, nullptr, nullptr,
                                               (float*)d_out, N);
}

// Round 4
// 262.495 us; speedup vs baseline: 2.0200x; 1.4867x over previous
//
#include <hip/hip_runtime.h>
#include <hip/hip_fp16.h>

#define BN_EPS 1e-5f

// ================= bucketed CSR build =================
// bucket = dst >> 8  (256 nodes per bucket), B = (N+255)>>8  (196 for N=50000)

// ---- pass 1: bucket totals via LDS histogram (2048 edges per block) ----
__global__ void k_bcount(const int* __restrict__ dst, int* __restrict__ btot, int E, int B) {
    __shared__ int cnt[256];
    int tid = threadIdx.x;
    cnt[tid] = 0;
    __syncthreads();
    int e0 = blockIdx.x * 2048;
#pragma unroll
    for (int j = 0; j < 8; ++j) {
        int e = e0 + j * 256 + tid;
        if (e < E) atomicAdd(&cnt[dst[e] >> 8], 1);
    }
    __syncthreads();
    if (tid < B && cnt[tid] > 0) atomicAdd(&btot[tid], cnt[tid]);
}

// ---- pass 2: scan bucket totals (B <= 256), init cursor, row_ptr[N] ----
__global__ void k_bscan(const int* __restrict__ btot, int* __restrict__ bbase,
                        int* __restrict__ bcur, int* __restrict__ row_ptr, int N, int B) {
    __shared__ int sc[256];
    int tid = threadIdx.x;
    int v = (tid < B) ? btot[tid] : 0;
    sc[tid] = v;
    __syncthreads();
    for (int off = 1; off < 256; off <<= 1) {
        int t = (tid >= off) ? sc[tid - off] : 0;
        __syncthreads();
        sc[tid] += t;
        __syncthreads();
    }
    int excl = sc[tid] - v;
    if (tid < B) { bbase[tid] = excl; bcur[tid] = excl; }
    if (tid == B - 1) { bbase[B] = excl + v; row_ptr[N] = excl + v; }
}

// ---- pass 3: coarse scatter into bucket-contiguous ebuf ----
// payload u32 = src | ((dst&255) << 16)
__global__ void k_bscatter(const int* __restrict__ src, const int* __restrict__ dst,
                           int* bcur, unsigned int* __restrict__ ebuf, int E, int B) {
    __shared__ int cnt[256];
    __shared__ int gb[256];
    int tid = threadIdx.x;
    cnt[tid] = 0;
    __syncthreads();
    int e0 = blockIdx.x * 2048;
    int bk[8], rk[8];
    unsigned int pay[8];
#pragma unroll
    for (int j = 0; j < 8; ++j) {
        int e = e0 + j * 256 + tid;
        if (e < E) {
            int d = dst[e];
            int b = d >> 8;
            bk[j] = b;
            rk[j] = atomicAdd(&cnt[b], 1);
            pay[j] = (unsigned int)src[e] | ((unsigned int)(d & 255) << 16);
        } else {
            bk[j] = -1; rk[j] = 0; pay[j] = 0;
        }
    }
    __syncthreads();
    if (tid < B && cnt[tid] > 0) gb[tid] = atomicAdd(&bcur[tid], cnt[tid]);
    __syncthreads();
#pragma unroll
    for (int j = 0; j < 8; ++j)
        if (bk[j] >= 0) ebuf[gb[bk[j]] + rk[j]] = pay[j];
}

// ---- pass 4: per-bucket finalize: hist -> scan -> row_ptr/dinv -> fine scatter ----
__global__ void k_bfinal(const unsigned int* __restrict__ ebuf, const int* __restrict__ bbase,
                         int* __restrict__ row_ptr, float* __restrict__ dinv,
                         unsigned short* __restrict__ col, int N) {
    __shared__ int cnt[256];
    __shared__ int sc[256];
    __shared__ int cur[256];
    int tid = threadIdx.x;
    int b = blockIdx.x;
    int node0 = b << 8;
    int ebeg = bbase[b], eend = bbase[b + 1];

    cnt[tid] = 0;
    __syncthreads();
    for (int i = ebeg + tid; i < eend; i += 256)
        atomicAdd(&cnt[ebuf[i] >> 16], 1);
    __syncthreads();
    int myc = cnt[tid];
    sc[tid] = myc;
    __syncthreads();
    for (int off = 1; off < 256; off <<= 1) {
        int t = (tid >= off) ? sc[tid - off] : 0;
        __syncthreads();
        sc[tid] += t;
        __syncthreads();
    }
    int excl = sc[tid] - myc;
    cur[tid] = ebeg + excl;
    int node = node0 + tid;
    if (node < N) {
        row_ptr[node] = ebeg + excl;
        dinv[node] = rsqrtf((float)(myc + 1));  // +1 self-loop
    }
    __syncthreads();
    for (int i = ebeg + tid; i < eend; i += 256) {
        unsigned int p = ebuf[i];
        int dl = p >> 16;
        int pos = atomicAdd(&cur[dl], 1);
        col[pos] = (unsigned short)(p & 0xFFFFu);
    }
}

// ================= GEMM with dinv-prescale epilogue, fp16 output =================
template <int K, int FOUT>
__launch_bounds__(256)
__global__ void k_gemm_scale(const float* __restrict__ X, const float* __restrict__ W,
                             const float* __restrict__ dinv, __half* __restrict__ HS, int N) {
    __shared__ float xs[K][65];
    __shared__ float wl[K][FOUT];
    int tid = threadIdx.x;
    int row0 = blockIdx.x * 64;

    for (int idx = tid; idx < K * FOUT; idx += 256)
        wl[idx / FOUT][idx % FOUT] = W[idx];
    for (int idx = tid; idx < 64 * K; idx += 256) {
        int r = idx / K, k = idx % K;
        int row = row0 + r;
        xs[k][r] = (row < N) ? X[row * K + k] : 0.0f;
    }
    __syncthreads();

    int tc = tid & 15, tr = tid >> 4;
    if (4 * tc < FOUT) {
        float acc[4][4] = {};
#pragma unroll 8
        for (int k = 0; k < K; ++k) {
            float a0 = xs[k][4 * tr + 0];
            float a1 = xs[k][4 * tr + 1];
            float a2 = xs[k][4 * tr + 2];
            float a3 = xs[k][4 * tr + 3];
            const float4 w = *reinterpret_cast<const float4*>(&wl[k][4 * tc]);
            acc[0][0] += a0 * w.x; acc[0][1] += a0 * w.y; acc[0][2] += a0 * w.z; acc[0][3] += a0 * w.w;
            acc[1][0] += a1 * w.x; acc[1][1] += a1 * w.y; acc[1][2] += a1 * w.z; acc[1][3] += a1 * w.w;
            acc[2][0] += a2 * w.x; acc[2][1] += a2 * w.y; acc[2][2] += a2 * w.z; acc[2][3] += a2 * w.w;
            acc[3][0] += a3 * w.x; acc[3][1] += a3 * w.y; acc[3][2] += a3 * w.z; acc[3][3] += a3 * w.w;
        }
#pragma unroll
        for (int i = 0; i < 4; ++i) {
            int row = row0 + 4 * tr + i;
            if (row < N) {
                float dv = dinv[row];
                __half2 h0 = __floats2half2_rn(dv * acc[i][0], dv * acc[i][1]);
                __half2 h1 = __floats2half2_rn(dv * acc[i][2], dv * acc[i][3]);
                __half2* p = reinterpret_cast<__half2*>(&HS[row * FOUT + 4 * tc]);
                p[0] = h0; p[1] = h1;
            }
        }
    }
}

// ================= Aggregation =================
template <int FOUT, bool BN>
__launch_bounds__(256)
__global__ void k_agg(const __half2* __restrict__ hs2, const unsigned short* __restrict__ col,
                      const int* __restrict__ row_ptr, const float* __restrict__ dinv,
                      const float* __restrict__ b, const float* __restrict__ g,
                      const float* __restrict__ be, const float* __restrict__ m,
                      const float* __restrict__ v, float* __restrict__ out, int N) {
    constexpr int NP = FOUT / 2;  // half2 per row
    int gtid = blockIdx.x * blockDim.x + threadIdx.x;
    int wave = gtid >> 6;
    int lane = gtid & 63;
    int half = lane >> 5;
    int l = lane & 31;
    int nwaves = (gridDim.x * blockDim.x) >> 6;
    bool active = l < NP;

    float b0 = 0.f, b1 = 0.f, s0f = 0.f, s1f = 0.f, t0f = 0.f, t1f = 0.f;
    if (active) {
        b0 = b[2 * l]; b1 = b[2 * l + 1];
        if (BN) {
            s0f = g[2 * l] * rsqrtf(v[2 * l] + BN_EPS);
            s1f = g[2 * l + 1] * rsqrtf(v[2 * l + 1] + BN_EPS);
            t0f = be[2 * l] - m[2 * l] * s0f;
            t1f = be[2 * l + 1] - m[2 * l + 1] * s1f;
        }
    }

    float2* out2 = reinterpret_cast<float2*>(out);

    for (int node = wave; node < N; node += nwaves) {
        int beg = row_ptr[node], end = row_ptr[node + 1];
        float ax = 0.f, ay = 0.f, bx = 0.f, by = 0.f;
        float cx = 0.f, cy = 0.f, dx = 0.f, dy = 0.f;
        if (active && half == 0) {
            float2 t = __half22float2(hs2[node * NP + l]);
            ax = t.x; ay = t.y;
        }
        int e = beg + half;
        for (; e + 6 < end; e += 8) {
            int i0 = col[e], i1 = col[e + 2], i2 = col[e + 4], i3 = col[e + 6];
            if (active) {
                float2 t0 = __half22float2(hs2[i0 * NP + l]);
                float2 t1 = __half22float2(hs2[i1 * NP + l]);
                float2 t2 = __half22float2(hs2[i2 * NP + l]);
                float2 t3 = __half22float2(hs2[i3 * NP + l]);
                ax += t0.x; ay += t0.y;
                bx += t1.x; by += t1.y;
                cx += t2.x; cy += t2.y;
                dx += t3.x; dy += t3.y;
            }
        }
        for (; e < end; e += 2) {
            int i0 = col[e];
            if (active) {
                float2 t0 = __half22float2(hs2[i0 * NP + l]);
                ax += t0.x; ay += t0.y;
            }
        }
        float sx = (ax + bx) + (cx + dx);
        float sy = (ay + by) + (cy + dy);
        sx += __shfl_xor(sx, 32);
        sy += __shfl_xor(sy, 32);
        if (active && half == 0) {
            float dv = dinv[node];
            float o0 = dv * sx + b0;
            float o1 = dv * sy + b1;
            if (BN) {
                o0 = fmaxf(o0 * s0f + t0f, 0.0f);
                o1 = fmaxf(o1 * s1f + t1f, 0.0f);
            }
            out2[node * NP + l] = make_float2(o0, o1);
        }
    }
}

// ================= launch =================

extern "C" void kernel_launch(void* const* d_in, const int* in_sizes, int n_in,
                              void* d_out, int out_size, void* d_ws, size_t ws_size,
                              hipStream_t stream) {
    const float* x   = (const float*)d_in[0];
    const int*   ei  = (const int*)d_in[1];
    const float* W1  = (const float*)d_in[2];
    const float* b1  = (const float*)d_in[3];
    const float* g1  = (const float*)d_in[4];
    const float* be1 = (const float*)d_in[5];
    const float* m1  = (const float*)d_in[6];
    const float* v1  = (const float*)d_in[7];
    const float* W2  = (const float*)d_in[8];
    const float* b2  = (const float*)d_in[9];
    const float* g2  = (const float*)d_in[10];
    const float* be2 = (const float*)d_in[11];
    const float* m2  = (const float*)d_in[12];
    const float* v2  = (const float*)d_in[13];
    const float* W3  = (const float*)d_in[14];
    const float* b3  = (const float*)d_in[15];

    const int FIN = 128, H = 64;
    int N = in_sizes[0] / FIN;       // 50000
    int E = in_sizes[1] / 2;         // 1600000
    const int* src = ei;
    const int* dst = ei + E;
    int B = (N + 255) >> 8;          // 196 buckets

    char* ws = (char*)d_ws;
    size_t off = 0;
    auto carve = [&](size_t bytes) -> void* {
        void* p = ws + off;
        off += (bytes + 255) & ~(size_t)255;
        return p;
    };
    float*  dinv    = (float*)carve((size_t)N * 4);
    int*    row_ptr = (int*)carve((size_t)(N + 1) * 4);
    unsigned short* col = (unsigned short*)carve((size_t)E * 2);
    unsigned int*   ebuf = (unsigned int*)carve((size_t)E * 4);
    __half* hs      = (__half*)carve((size_t)N * H * 2);
    float*  y       = (float*)carve((size_t)N * H * 4);
    int*    btot    = (int*)carve(512 * 4);
    int*    bbase   = (int*)carve(512 * 4);
    int*    bcur    = (int*)carve(512 * 4);
    (void)ws_size; (void)n_in; (void)out_size;

    int eb2k = (E + 2047) / 2048;

    hipMemsetAsync(btot, 0, (size_t)B * 4, stream);
    k_bcount<<<eb2k, 256, 0, stream>>>(dst, btot, E, B);
    k_bscan<<<1, 256, 0, stream>>>(btot, bbase, bcur, row_ptr, N, B);
    k_bscatter<<<eb2k, 256, 0, stream>>>(src, dst, bcur, ebuf, E, B);
    k_bfinal<<<B, 256, 0, stream>>>(ebuf, bbase, row_ptr, dinv, col, N);

    int gb = (N + 63) / 64;
    const __half2* hs2 = (const __half2*)hs;
    // layer 1
    k_gemm_scale<128, 64><<<gb, 256, 0, stream>>>(x, W1, dinv, hs, N);
    k_agg<64, true><<<4096, 256, 0, stream>>>(hs2, col, row_ptr, dinv, b1, g1, be1, m1, v1, y, N);
    // layer 2
    k_gemm_scale<64, 64><<<gb, 256, 0, stream>>>(y, W2, dinv, hs, N);
    k_agg<64, true><<<4096, 256, 0, stream>>>(hs2, col, row_ptr, dinv, b2, g2, be2, m2, v2, y, N);
    // layer 3
    k_gemm_scale<64, 40><<<gb, 256, 0, stream>>>(y, W3, dinv, hs, N);
    k_agg<40, false><<<4096, 256, 0, stream>>>(hs2, col, row_ptr, dinv, b3, nullptr, nullptr, nullptr, nullptr,
                                               (float*)d_out, N);
}

// Round 5
// 235.583 us; speedup vs baseline: 2.2508x; 1.1142x over previous
//
#include <hip/hip_runtime.h>
#include <hip/hip_fp16.h>

#define BN_EPS 1e-5f

typedef _Float16 half2_t __attribute__((ext_vector_type(2)));
typedef _Float16 half8_t __attribute__((ext_vector_type(8)));

static __device__ __forceinline__ float fdot2(half2_t a, half2_t b, float c) {
    return __builtin_amdgcn_fdot2(a, b, c, false);
}

// ================= bucketed CSR build =================
// bucket = dst >> 8  (256 nodes per bucket), B = (N+255)>>8  (196 for N=50000)

__global__ void k_bcount(const int* __restrict__ dst, int* __restrict__ btot, int E, int B) {
    __shared__ int cnt[256];
    int tid = threadIdx.x;
    cnt[tid] = 0;
    __syncthreads();
    int e0 = blockIdx.x * 2048;
#pragma unroll
    for (int j = 0; j < 8; ++j) {
        int e = e0 + j * 256 + tid;
        if (e < E) atomicAdd(&cnt[dst[e] >> 8], 1);
    }
    __syncthreads();
    if (tid < B && cnt[tid] > 0) atomicAdd(&btot[tid], cnt[tid]);
}

__global__ void k_bscan(const int* __restrict__ btot, int* __restrict__ bbase,
                        int* __restrict__ bcur, int* __restrict__ row_ptr, int N, int B) {
    __shared__ int sc[256];
    int tid = threadIdx.x;
    int v = (tid < B) ? btot[tid] : 0;
    sc[tid] = v;
    __syncthreads();
    for (int off = 1; off < 256; off <<= 1) {
        int t = (tid >= off) ? sc[tid - off] : 0;
        __syncthreads();
        sc[tid] += t;
        __syncthreads();
    }
    int excl = sc[tid] - v;
    if (tid < B) { bbase[tid] = excl; bcur[tid] = excl; }
    if (tid == B - 1) { bbase[B] = excl + v; row_ptr[N] = excl + v; }
}

// payload u32 = src | ((dst&255) << 16)
__global__ void k_bscatter(const int* __restrict__ src, const int* __restrict__ dst,
                           int* bcur, unsigned int* __restrict__ ebuf, int E, int B) {
    __shared__ int cnt[256];
    __shared__ int gb[256];
    int tid = threadIdx.x;
    cnt[tid] = 0;
    __syncthreads();
    int e0 = blockIdx.x * 2048;
    int bk[8], rk[8];
    unsigned int pay[8];
#pragma unroll
    for (int j = 0; j < 8; ++j) {
        int e = e0 + j * 256 + tid;
        if (e < E) {
            int d = dst[e];
            int b = d >> 8;
            bk[j] = b;
            rk[j] = atomicAdd(&cnt[b], 1);
            pay[j] = (unsigned int)src[e] | ((unsigned int)(d & 255) << 16);
        } else {
            bk[j] = -1; rk[j] = 0; pay[j] = 0;
        }
    }
    __syncthreads();
    if (tid < B && cnt[tid] > 0) gb[tid] = atomicAdd(&bcur[tid], cnt[tid]);
    __syncthreads();
#pragma unroll
    for (int j = 0; j < 8; ++j)
        if (bk[j] >= 0) ebuf[gb[bk[j]] + rk[j]] = pay[j];
}

__global__ void k_bfinal(const unsigned int* __restrict__ ebuf, const int* __restrict__ bbase,
                         int* __restrict__ row_ptr, float* __restrict__ dinv,
                         unsigned short* __restrict__ col, int N) {
    __shared__ int cnt[256];
    __shared__ int sc[256];
    __shared__ int cur[256];
    int tid = threadIdx.x;
    int b = blockIdx.x;
    int node0 = b << 8;
    int ebeg = bbase[b], eend = bbase[b + 1];

    cnt[tid] = 0;
    __syncthreads();
    for (int i = ebeg + tid; i < eend; i += 256)
        atomicAdd(&cnt[ebuf[i] >> 16], 1);
    __syncthreads();
    int myc = cnt[tid];
    sc[tid] = myc;
    __syncthreads();
    for (int off = 1; off < 256; off <<= 1) {
        int t = (tid >= off) ? sc[tid - off] : 0;
        __syncthreads();
        sc[tid] += t;
        __syncthreads();
    }
    int excl = sc[tid] - myc;
    cur[tid] = ebeg + excl;
    int node = node0 + tid;
    if (node < N) {
        row_ptr[node] = ebeg + excl;
        dinv[node] = rsqrtf((float)(myc + 1));  // +1 self-loop
    }
    __syncthreads();
    for (int i = ebeg + tid; i < eend; i += 256) {
        unsigned int p = ebuf[i];
        int dl = p >> 16;
        int pos = atomicAdd(&cur[dl], 1);
        col[pos] = (unsigned short)(p & 0xFFFFu);
    }
}

// ================= GEMM (fp16 operands, fdot2, f32 accum) =================
// HS[row][f] = fp16( dinv[row] * (X @ W)[row][f] )
// 64-row tile per block, 256 threads, thread (tr,tc) computes 4 rows x 4 cols.
template <int K, int FOUT, bool FP16IN>
__launch_bounds__(256)
__global__ void k_gemm_scale(const void* __restrict__ Xv, const float* __restrict__ W,
                             const float* __restrict__ dinv, half2_t* __restrict__ HS, int N) {
    constexpr int KK = K / 2;                   // half2 per row
    constexpr int XSTR = (K == 128) ? 66 : 36;  // padded row stride (half2)
    __shared__ half2_t xs2[64][XSTR];
    __shared__ half2_t wl2[KK][FOUT];
    int tid = threadIdx.x;
    int row0 = blockIdx.x * 64;

    // stage X tile -> fp16 LDS
    if constexpr (FP16IN) {
        const _Float16* X = (const _Float16*)Xv;
        constexpr int U = 64 * K / 8;  // 16B units
        for (int u = tid; u < U; u += 256) {
            int row = u / (K / 8), q = u % (K / 8);
            int grow = row0 + row;
            uint4 v = make_uint4(0u, 0u, 0u, 0u);
            if (grow < N) v = *(const uint4*)&X[(size_t)grow * K + q * 8];
            *(uint4*)&xs2[row][q * 4] = v;
        }
    } else {
        const float* X = (const float*)Xv;
        constexpr int U = 64 * K / 4;  // float4 units
        for (int u = tid; u < U; u += 256) {
            int row = u / (K / 4), c = u % (K / 4);
            int grow = row0 + row;
            half2_t h0 = (half2_t)(_Float16)0, h1 = (half2_t)(_Float16)0;
            if (grow < N) {
                float4 v = *(const float4*)&X[(size_t)grow * K + c * 4];
                h0[0] = (_Float16)v.x; h0[1] = (_Float16)v.y;
                h1[0] = (_Float16)v.z; h1[1] = (_Float16)v.w;
            }
            xs2[row][2 * c] = h0;
            xs2[row][2 * c + 1] = h1;
        }
    }
    // stage W -> fp16 LDS, pairing k and k+1
    for (int i = tid; i < KK * FOUT; i += 256) {
        int kk = i / FOUT, f = i % FOUT;
        half2_t h;
        h[0] = (_Float16)W[(2 * kk) * FOUT + f];
        h[1] = (_Float16)W[(2 * kk + 1) * FOUT + f];
        wl2[kk][f] = h;
    }
    __syncthreads();

    int tc = tid & 15, tr = tid >> 4;
    if (4 * tc < FOUT) {
        float acc[4][4] = {};
#pragma unroll 4
        for (int kk = 0; kk < KK; ++kk) {
            half2_t a0 = xs2[4 * tr + 0][kk];
            half2_t a1 = xs2[4 * tr + 1][kk];
            half2_t a2 = xs2[4 * tr + 2][kk];
            half2_t a3 = xs2[4 * tr + 3][kk];
            half8_t wv = *(const half8_t*)&wl2[kk][4 * tc];
            half2_t w0 = {wv[0], wv[1]};
            half2_t w1 = {wv[2], wv[3]};
            half2_t w2 = {wv[4], wv[5]};
            half2_t w3 = {wv[6], wv[7]};
            acc[0][0] = fdot2(a0, w0, acc[0][0]); acc[0][1] = fdot2(a0, w1, acc[0][1]);
            acc[0][2] = fdot2(a0, w2, acc[0][2]); acc[0][3] = fdot2(a0, w3, acc[0][3]);
            acc[1][0] = fdot2(a1, w0, acc[1][0]); acc[1][1] = fdot2(a1, w1, acc[1][1]);
            acc[1][2] = fdot2(a1, w2, acc[1][2]); acc[1][3] = fdot2(a1, w3, acc[1][3]);
            acc[2][0] = fdot2(a2, w0, acc[2][0]); acc[2][1] = fdot2(a2, w1, acc[2][1]);
            acc[2][2] = fdot2(a2, w2, acc[2][2]); acc[2][3] = fdot2(a2, w3, acc[2][3]);
            acc[3][0] = fdot2(a3, w0, acc[3][0]); acc[3][1] = fdot2(a3, w1, acc[3][1]);
            acc[3][2] = fdot2(a3, w2, acc[3][2]); acc[3][3] = fdot2(a3, w3, acc[3][3]);
        }
#pragma unroll
        for (int i = 0; i < 4; ++i) {
            int row = row0 + 4 * tr + i;
            if (row < N) {
                float dv = dinv[row];
                half2_t p0, p1;
                p0[0] = (_Float16)(dv * acc[i][0]); p0[1] = (_Float16)(dv * acc[i][1]);
                p1[0] = (_Float16)(dv * acc[i][2]); p1[1] = (_Float16)(dv * acc[i][3]);
                HS[(size_t)row * (FOUT / 2) + 2 * tc] = p0;
                HS[(size_t)row * (FOUT / 2) + 2 * tc + 1] = p1;
            }
        }
    }
}

// ================= Aggregation =================
// one wave per node; halves of the wave take alternating edges; BN layers emit fp16.
template <int FOUT, bool BN>
__launch_bounds__(256)
__global__ void k_agg(const half2_t* __restrict__ hs2, const unsigned short* __restrict__ col,
                      const int* __restrict__ row_ptr, const float* __restrict__ dinv,
                      const float* __restrict__ b, const float* __restrict__ g,
                      const float* __restrict__ be, const float* __restrict__ m,
                      const float* __restrict__ v, void* __restrict__ outv, int N) {
    constexpr int NP = FOUT / 2;  // half2 per row
    int gtid = blockIdx.x * blockDim.x + threadIdx.x;
    int wave = gtid >> 6;
    int lane = gtid & 63;
    int half = lane >> 5;
    int l = lane & 31;
    int nwaves = (gridDim.x * blockDim.x) >> 6;
    bool active = l < NP;

    float b0 = 0.f, b1 = 0.f, s0f = 0.f, s1f = 0.f, t0f = 0.f, t1f = 0.f;
    if (active) {
        b0 = b[2 * l]; b1 = b[2 * l + 1];
        if (BN) {
            s0f = g[2 * l] * rsqrtf(v[2 * l] + BN_EPS);
            s1f = g[2 * l + 1] * rsqrtf(v[2 * l + 1] + BN_EPS);
            t0f = be[2 * l] - m[2 * l] * s0f;
            t1f = be[2 * l + 1] - m[2 * l + 1] * s1f;
        }
    }

    for (int node = wave; node < N; node += nwaves) {
        int beg = row_ptr[node], end = row_ptr[node + 1];
        float ax = 0.f, ay = 0.f, bx = 0.f, by = 0.f;
        float cx = 0.f, cy = 0.f, dx = 0.f, dy = 0.f;
        if (active && half == 0) {
            half2_t t = hs2[(size_t)node * NP + l];
            ax = (float)t[0]; ay = (float)t[1];
        }
        int e = beg + half;
        for (; e + 6 < end; e += 8) {
            int i0 = col[e], i1 = col[e + 2], i2 = col[e + 4], i3 = col[e + 6];
            if (active) {
                half2_t t0 = hs2[(size_t)i0 * NP + l];
                half2_t t1 = hs2[(size_t)i1 * NP + l];
                half2_t t2 = hs2[(size_t)i2 * NP + l];
                half2_t t3 = hs2[(size_t)i3 * NP + l];
                ax += (float)t0[0]; ay += (float)t0[1];
                bx += (float)t1[0]; by += (float)t1[1];
                cx += (float)t2[0]; cy += (float)t2[1];
                dx += (float)t3[0]; dy += (float)t3[1];
            }
        }
        for (; e < end; e += 2) {
            int i0 = col[e];
            if (active) {
                half2_t t0 = hs2[(size_t)i0 * NP + l];
                ax += (float)t0[0]; ay += (float)t0[1];
            }
        }
        float sx = (ax + bx) + (cx + dx);
        float sy = (ay + by) + (cy + dy);
        sx += __shfl_xor(sx, 32);
        sy += __shfl_xor(sy, 32);
        if (active && half == 0) {
            float dv = dinv[node];
            float o0 = dv * sx + b0;
            float o1 = dv * sy + b1;
            if (BN) {
                o0 = fmaxf(o0 * s0f + t0f, 0.0f);
                o1 = fmaxf(o1 * s1f + t1f, 0.0f);
                half2_t h;
                h[0] = (_Float16)o0; h[1] = (_Float16)o1;
                ((half2_t*)outv)[(size_t)node * NP + l] = h;
            } else {
                ((float2*)outv)[(size_t)node * NP + l] = make_float2(o0, o1);
            }
        }
    }
}

// ================= launch =================

extern "C" void kernel_launch(void* const* d_in, const int* in_sizes, int n_in,
                              void* d_out, int out_size, void* d_ws, size_t ws_size,
                              hipStream_t stream) {
    const float* x   = (const float*)d_in[0];
    const int*   ei  = (const int*)d_in[1];
    const float* W1  = (const float*)d_in[2];
    const float* b1  = (const float*)d_in[3];
    const float* g1  = (const float*)d_in[4];
    const float* be1 = (const float*)d_in[5];
    const float* m1  = (const float*)d_in[6];
    const float* v1  = (const float*)d_in[7];
    const float* W2  = (const float*)d_in[8];
    const float* b2  = (const float*)d_in[9];
    const float* g2  = (const float*)d_in[10];
    const float* be2 = (const float*)d_in[11];
    const float* m2  = (const float*)d_in[12];
    const float* v2  = (const float*)d_in[13];
    const float* W3  = (const float*)d_in[14];
    const float* b3  = (const float*)d_in[15];

    const int FIN = 128, H = 64;
    int N = in_sizes[0] / FIN;       // 50000
    int E = in_sizes[1] / 2;         // 1600000
    const int* src = ei;
    const int* dst = ei + E;
    int B = (N + 255) >> 8;          // 196 buckets

    char* ws = (char*)d_ws;
    size_t off = 0;
    auto carve = [&](size_t bytes) -> void* {
        void* p = ws + off;
        off += (bytes + 255) & ~(size_t)255;
        return p;
    };
    float*  dinv    = (float*)carve((size_t)N * 4);
    int*    row_ptr = (int*)carve((size_t)(N + 1) * 4);
    unsigned short* col = (unsigned short*)carve((size_t)E * 2);
    unsigned int*   ebuf = (unsigned int*)carve((size_t)E * 4);
    half2_t* hs     = (half2_t*)carve((size_t)N * H * 2);
    _Float16* y     = (_Float16*)carve((size_t)N * H * 2);
    int*    btot    = (int*)carve(512 * 4);
    int*    bbase   = (int*)carve(512 * 4);
    int*    bcur    = (int*)carve(512 * 4);
    (void)ws_size; (void)n_in; (void)out_size;

    int eb2k = (E + 2047) / 2048;

    hipMemsetAsync(btot, 0, (size_t)B * 4, stream);
    k_bcount<<<eb2k, 256, 0, stream>>>(dst, btot, E, B);
    k_bscan<<<1, 256, 0, stream>>>(btot, bbase, bcur, row_ptr, N, B);
    k_bscatter<<<eb2k, 256, 0, stream>>>(src, dst, bcur, ebuf, E, B);
    k_bfinal<<<B, 256, 0, stream>>>(ebuf, bbase, row_ptr, dinv, col, N);

    int gb = (N + 63) / 64;
    // layer 1
    k_gemm_scale<128, 64, false><<<gb, 256, 0, stream>>>(x, W1, dinv, hs, N);
    k_agg<64, true><<<4096, 256, 0, stream>>>(hs, col, row_ptr, dinv, b1, g1, be1, m1, v1, y, N);
    // layer 2
    k_gemm_scale<64, 64, true><<<gb, 256, 0, stream>>>(y, W2, dinv, hs, N);
    k_agg<64, true><<<4096, 256, 0, stream>>>(hs, col, row_ptr, dinv, b2, g2, be2, m2, v2, y, N);
    // layer 3
    k_gemm_scale<64, 40, true><<<gb, 256, 0, stream>>>(y, W3, dinv, hs, N);
    k_agg<40, false><<<4096, 256, 0, stream>>>(hs, col, row_ptr, dinv, b3, nullptr, nullptr, nullptr, nullptr,
                                               d_out, N);
}

// Round 6
// 233.960 us; speedup vs baseline: 2.2664x; 1.0069x over previous
//
#include <hip/hip_runtime.h>
#include <hip/hip_fp16.h>

#define BN_EPS 1e-5f

typedef _Float16 half2_t __attribute__((ext_vector_type(2)));
typedef _Float16 half8_t __attribute__((ext_vector_type(8)));

static __device__ __forceinline__ float fdot2(half2_t a, half2_t b, float c) {
    return __builtin_amdgcn_fdot2(a, b, c, false);
}

// ================= bucketed CSR build =================
// bucket = dst >> 8  (256 nodes per bucket), B = (N+255)>>8  (196 for N=50000)

__global__ void k_zero(int* __restrict__ p, int n) {
    int i = threadIdx.x;
    if (i < n) p[i] = 0;
}

__global__ void k_bcount(const int* __restrict__ dst, int* __restrict__ btot, int E, int B) {
    __shared__ int cnt[256];
    int tid = threadIdx.x;
    cnt[tid] = 0;
    __syncthreads();
    int e0 = blockIdx.x * 2048;
#pragma unroll
    for (int j = 0; j < 8; ++j) {
        int e = e0 + j * 256 + tid;
        if (e < E) atomicAdd(&cnt[dst[e] >> 8], 1);
    }
    __syncthreads();
    if (tid < B && cnt[tid] > 0) atomicAdd(&btot[tid], cnt[tid]);
}

__global__ void k_bscan(const int* __restrict__ btot, int* __restrict__ bbase,
                        int* __restrict__ bcur, int* __restrict__ row_ptr, int N, int B) {
    __shared__ int sc[256];
    int tid = threadIdx.x;
    int v = (tid < B) ? btot[tid] : 0;
    sc[tid] = v;
    __syncthreads();
    for (int off = 1; off < 256; off <<= 1) {
        int t = (tid >= off) ? sc[tid - off] : 0;
        __syncthreads();
        sc[tid] += t;
        __syncthreads();
    }
    int excl = sc[tid] - v;
    if (tid < B) { bbase[tid] = excl; bcur[tid] = excl; }
    if (tid == B - 1) { bbase[B] = excl + v; row_ptr[N] = excl + v; }
}

// payload u32 = src | ((dst&255) << 16)
__global__ void k_bscatter(const int* __restrict__ src, const int* __restrict__ dst,
                           int* bcur, unsigned int* __restrict__ ebuf, int E, int B) {
    __shared__ int cnt[256];
    __shared__ int gb[256];
    int tid = threadIdx.x;
    cnt[tid] = 0;
    __syncthreads();
    int e0 = blockIdx.x * 2048;
    int bk[8], rk[8];
    unsigned int pay[8];
#pragma unroll
    for (int j = 0; j < 8; ++j) {
        int e = e0 + j * 256 + tid;
        if (e < E) {
            int d = dst[e];
            int b = d >> 8;
            bk[j] = b;
            rk[j] = atomicAdd(&cnt[b], 1);
            pay[j] = (unsigned int)src[e] | ((unsigned int)(d & 255) << 16);
        } else {
            bk[j] = -1; rk[j] = 0; pay[j] = 0;
        }
    }
    __syncthreads();
    if (tid < B && cnt[tid] > 0) gb[tid] = atomicAdd(&bcur[tid], cnt[tid]);
    __syncthreads();
#pragma unroll
    for (int j = 0; j < 8; ++j)
        if (bk[j] >= 0) ebuf[gb[bk[j]] + rk[j]] = pay[j];
}

__global__ void k_bfinal(const unsigned int* __restrict__ ebuf, const int* __restrict__ bbase,
                         int* __restrict__ row_ptr, float* __restrict__ dinv,
                         unsigned short* __restrict__ col, int N) {
    __shared__ int cnt[256];
    __shared__ int sc[256];
    __shared__ int cur[256];
    int tid = threadIdx.x;
    int b = blockIdx.x;
    int node0 = b << 8;
    int ebeg = bbase[b], eend = bbase[b + 1];

    cnt[tid] = 0;
    __syncthreads();
    for (int i = ebeg + tid; i < eend; i += 256)
        atomicAdd(&cnt[ebuf[i] >> 16], 1);
    __syncthreads();
    int myc = cnt[tid];
    sc[tid] = myc;
    __syncthreads();
    for (int off = 1; off < 256; off <<= 1) {
        int t = (tid >= off) ? sc[tid - off] : 0;
        __syncthreads();
        sc[tid] += t;
        __syncthreads();
    }
    int excl = sc[tid] - myc;
    cur[tid] = ebeg + excl;
    int node = node0 + tid;
    if (node < N) {
        row_ptr[node] = ebeg + excl;
        dinv[node] = rsqrtf((float)(myc + 1));  // +1 self-loop
    }
    __syncthreads();
    for (int i = ebeg + tid; i < eend; i += 256) {
        unsigned int p = ebuf[i];
        int dl = p >> 16;
        int pos = atomicAdd(&cur[dl], 1);
        col[pos] = (unsigned short)(p & 0xFFFFu);
    }
}

// ================= GEMM (fp16 operands, fdot2, f32 accum) =================
template <int K, int FOUT, bool FP16IN>
__launch_bounds__(256)
__global__ void k_gemm_scale(const void* __restrict__ Xv, const float* __restrict__ W,
                             const float* __restrict__ dinv, half2_t* __restrict__ HS, int N) {
    constexpr int KK = K / 2;                   // half2 per row
    constexpr int XSTR = (K == 128) ? 66 : 36;  // padded row stride (half2)
    __shared__ half2_t xs2[64][XSTR];
    __shared__ half2_t wl2[KK][FOUT];
    int tid = threadIdx.x;
    int row0 = blockIdx.x * 64;

    if constexpr (FP16IN) {
        const _Float16* X = (const _Float16*)Xv;
        constexpr int U = 64 * K / 8;  // 16B units
        for (int u = tid; u < U; u += 256) {
            int row = u / (K / 8), q = u % (K / 8);
            int grow = row0 + row;
            uint4 v = make_uint4(0u, 0u, 0u, 0u);
            if (grow < N) v = *(const uint4*)&X[(size_t)grow * K + q * 8];
            *(uint4*)&xs2[row][q * 4] = v;
        }
    } else {
        const float* X = (const float*)Xv;
        constexpr int U = 64 * K / 4;  // float4 units
        for (int u = tid; u < U; u += 256) {
            int row = u / (K / 4), c = u % (K / 4);
            int grow = row0 + row;
            half2_t h0 = (half2_t)(_Float16)0, h1 = (half2_t)(_Float16)0;
            if (grow < N) {
                float4 v = *(const float4*)&X[(size_t)grow * K + c * 4];
                h0[0] = (_Float16)v.x; h0[1] = (_Float16)v.y;
                h1[0] = (_Float16)v.z; h1[1] = (_Float16)v.w;
            }
            xs2[row][2 * c] = h0;
            xs2[row][2 * c + 1] = h1;
        }
    }
    for (int i = tid; i < KK * FOUT; i += 256) {
        int kk = i / FOUT, f = i % FOUT;
        half2_t h;
        h[0] = (_Float16)W[(2 * kk) * FOUT + f];
        h[1] = (_Float16)W[(2 * kk + 1) * FOUT + f];
        wl2[kk][f] = h;
    }
    __syncthreads();

    int tc = tid & 15, tr = tid >> 4;
    if (4 * tc < FOUT) {
        float acc[4][4] = {};
#pragma unroll 4
        for (int kk = 0; kk < KK; ++kk) {
            half2_t a0 = xs2[4 * tr + 0][kk];
            half2_t a1 = xs2[4 * tr + 1][kk];
            half2_t a2 = xs2[4 * tr + 2][kk];
            half2_t a3 = xs2[4 * tr + 3][kk];
            half8_t wv = *(const half8_t*)&wl2[kk][4 * tc];
            half2_t w0 = {wv[0], wv[1]};
            half2_t w1 = {wv[2], wv[3]};
            half2_t w2 = {wv[4], wv[5]};
            half2_t w3 = {wv[6], wv[7]};
            acc[0][0] = fdot2(a0, w0, acc[0][0]); acc[0][1] = fdot2(a0, w1, acc[0][1]);
            acc[0][2] = fdot2(a0, w2, acc[0][2]); acc[0][3] = fdot2(a0, w3, acc[0][3]);
            acc[1][0] = fdot2(a1, w0, acc[1][0]); acc[1][1] = fdot2(a1, w1, acc[1][1]);
            acc[1][2] = fdot2(a1, w2, acc[1][2]); acc[1][3] = fdot2(a1, w3, acc[1][3]);
            acc[2][0] = fdot2(a2, w0, acc[2][0]); acc[2][1] = fdot2(a2, w1, acc[2][1]);
            acc[2][2] = fdot2(a2, w2, acc[2][2]); acc[2][3] = fdot2(a2, w3, acc[2][3]);
            acc[3][0] = fdot2(a3, w0, acc[3][0]); acc[3][1] = fdot2(a3, w1, acc[3][1]);
            acc[3][2] = fdot2(a3, w2, acc[3][2]); acc[3][3] = fdot2(a3, w3, acc[3][3]);
        }
#pragma unroll
        for (int i = 0; i < 4; ++i) {
            int row = row0 + 4 * tr + i;
            if (row < N) {
                float dv = dinv[row];
                half2_t p0, p1;
                p0[0] = (_Float16)(dv * acc[i][0]); p0[1] = (_Float16)(dv * acc[i][1]);
                p1[0] = (_Float16)(dv * acc[i][2]); p1[1] = (_Float16)(dv * acc[i][3]);
                HS[(size_t)row * (FOUT / 2) + 2 * tc] = p0;
                HS[(size_t)row * (FOUT / 2) + 2 * tc + 1] = p1;
            }
        }
    }
}

// ================= Aggregation =================
template <int FOUT, bool BN>
__launch_bounds__(256)
__global__ void k_agg(const half2_t* __restrict__ hs2, const unsigned short* __restrict__ col,
                      const int* __restrict__ row_ptr, const float* __restrict__ dinv,
                      const float* __restrict__ b, const float* __restrict__ g,
                      const float* __restrict__ be, const float* __restrict__ m,
                      const float* __restrict__ v, void* __restrict__ outv, int N) {
    constexpr int NP = FOUT / 2;  // half2 per row
    int gtid = blockIdx.x * blockDim.x + threadIdx.x;
    int wave = gtid >> 6;
    int lane = gtid & 63;
    int half = lane >> 5;
    int l = lane & 31;
    int nwaves = (gridDim.x * blockDim.x) >> 6;
    bool active = l < NP;

    float b0 = 0.f, b1 = 0.f, s0f = 0.f, s1f = 0.f, t0f = 0.f, t1f = 0.f;
    if (active) {
        b0 = b[2 * l]; b1 = b[2 * l + 1];
        if (BN) {
            s0f = g[2 * l] * rsqrtf(v[2 * l] + BN_EPS);
            s1f = g[2 * l + 1] * rsqrtf(v[2 * l + 1] + BN_EPS);
            t0f = be[2 * l] - m[2 * l] * s0f;
            t1f = be[2 * l + 1] - m[2 * l + 1] * s1f;
        }
    }

    for (int node = wave; node < N; node += nwaves) {
        int beg = row_ptr[node], end = row_ptr[node + 1];
        float ax = 0.f, ay = 0.f, bx = 0.f, by = 0.f;
        float cx = 0.f, cy = 0.f, dx = 0.f, dy = 0.f;
        if (active && half == 0) {
            half2_t t = hs2[(size_t)node * NP + l];
            ax = (float)t[0]; ay = (float)t[1];
        }
        int e = beg + half;
        for (; e + 6 < end; e += 8) {
            int i0 = col[e], i1 = col[e + 2], i2 = col[e + 4], i3 = col[e + 6];
            if (active) {
                half2_t t0 = hs2[(size_t)i0 * NP + l];
                half2_t t1 = hs2[(size_t)i1 * NP + l];
                half2_t t2 = hs2[(size_t)i2 * NP + l];
                half2_t t3 = hs2[(size_t)i3 * NP + l];
                ax += (float)t0[0]; ay += (float)t0[1];
                bx += (float)t1[0]; by += (float)t1[1];
                cx += (float)t2[0]; cy += (float)t2[1];
                dx += (float)t3[0]; dy += (float)t3[1];
            }
        }
        for (; e < end; e += 2) {
            int i0 = col[e];
            if (active) {
                half2_t t0 = hs2[(size_t)i0 * NP + l];
                ax += (float)t0[0]; ay += (float)t0[1];
            }
        }
        float sx = (ax + bx) + (cx + dx);
        float sy = (ay + by) + (cy + dy);
        sx += __shfl_xor(sx, 32);
        sy += __shfl_xor(sy, 32);
        if (active && half == 0) {
            float dv = dinv[node];
            float o0 = dv * sx + b0;
            float o1 = dv * sy + b1;
            if (BN) {
                o0 = fmaxf(o0 * s0f + t0f, 0.0f);
                o1 = fmaxf(o1 * s1f + t1f, 0.0f);
                half2_t h;
                h[0] = (_Float16)o0; h[1] = (_Float16)o1;
                ((half2_t*)outv)[(size_t)node * NP + l] = h;
            } else {
                ((float2*)outv)[(size_t)node * NP + l] = make_float2(o0, o1);
            }
        }
    }
}

// ================= launch =================

extern "C" void kernel_launch(void* const* d_in, const int* in_sizes, int n_in,
                              void* d_out, int out_size, void* d_ws, size_t ws_size,
                              hipStream_t stream) {
    const float* x   = (const float*)d_in[0];
    const int*   ei  = (const int*)d_in[1];
    const float* W1  = (const float*)d_in[2];
    const float* b1  = (const float*)d_in[3];
    const float* g1  = (const float*)d_in[4];
    const float* be1 = (const float*)d_in[5];
    const float* m1  = (const float*)d_in[6];
    const float* v1  = (const float*)d_in[7];
    const float* W2  = (const float*)d_in[8];
    const float* b2  = (const float*)d_in[9];
    const float* g2  = (const float*)d_in[10];
    const float* be2 = (const float*)d_in[11];
    const float* m2  = (const float*)d_in[12];
    const float* v2  = (const float*)d_in[13];
    const float* W3  = (const float*)d_in[14];
    const float* b3  = (const float*)d_in[15];

    const int FIN = 128, H = 64;
    int N = in_sizes[0] / FIN;       // 50000
    int E = in_sizes[1] / 2;         // 1600000
    const int* src = ei;
    const int* dst = ei + E;
    int B = (N + 255) >> 8;          // 196 buckets

    char* ws = (char*)d_ws;
    size_t off = 0;
    auto carve = [&](size_t bytes) -> void* {
        void* p = ws + off;
        off += (bytes + 255) & ~(size_t)255;
        return p;
    };
    float*  dinv    = (float*)carve((size_t)N * 4);
    int*    row_ptr = (int*)carve((size_t)(N + 1) * 4);
    unsigned short* col = (unsigned short*)carve((size_t)E * 2);
    unsigned int*   ebuf = (unsigned int*)carve((size_t)E * 4);
    half2_t* hs     = (half2_t*)carve((size_t)N * H * 2);
    _Float16* y     = (_Float16*)carve((size_t)N * H * 2);
    int*    btot    = (int*)carve(512 * 4);
    int*    bbase   = (int*)carve(512 * 4);
    int*    bcur    = (int*)carve(512 * 4);
    (void)ws_size; (void)n_in; (void)out_size;

    int eb2k = (E + 2047) / 2048;

    k_zero<<<1, 256, 0, stream>>>(btot, B);
    k_bcount<<<eb2k, 256, 0, stream>>>(dst, btot, E, B);
    k_bscan<<<1, 256, 0, stream>>>(btot, bbase, bcur, row_ptr, N, B);
    k_bscatter<<<eb2k, 256, 0, stream>>>(src, dst, bcur, ebuf, E, B);
    k_bfinal<<<B, 256, 0, stream>>>(ebuf, bbase, row_ptr, dinv, col, N);

    int gb = (N + 63) / 64;
    // layer 1
    k_gemm_scale<128, 64, false><<<gb, 256, 0, stream>>>(x, W1, dinv, hs, N);
    k_agg<64, true><<<4096, 256, 0, stream>>>(hs, col, row_ptr, dinv, b1, g1, be1, m1, v1, y, N);
    // layer 2
    k_gemm_scale<64, 64, true><<<gb, 256, 0, stream>>>(y, W2, dinv, hs, N);
    k_agg<64, true><<<4096, 256, 0, stream>>>(hs, col, row_ptr, dinv, b2, g2, be2, m2, v2, y, N);
    // layer 3
    k_gemm_scale<64, 40, true><<<gb, 256, 0, stream>>>(y, W3, dinv, hs, N);
    k_agg<40, false><<<4096, 256, 0, stream>>>(hs, col, row_ptr, dinv, b3, nullptr, nullptr, nullptr, nullptr,
                                               d_out, N);
}

// Round 7
// 220.909 us; speedup vs baseline: 2.4003x; 1.0591x over previous
//
#include <hip/hip_runtime.h>
#include <hip/hip_fp16.h>

#define BN_EPS 1e-5f

typedef _Float16 half2_t __attribute__((ext_vector_type(2)));
typedef _Float16 half8_t __attribute__((ext_vector_type(8)));

static __device__ __forceinline__ float fdot2(half2_t a, half2_t b, float c) {
    return __builtin_amdgcn_fdot2(a, b, c, false);
}

// ================= bucketed CSR build =================
// bucket = dst >> 8  (256 nodes per bucket), B = (N+255)>>8  (196 for N=50000)

__global__ void k_zero(int* __restrict__ p, int n) {
    int i = threadIdx.x;
    if (i < n) p[i] = 0;
}

__global__ void k_bcount(const int* __restrict__ dst, int* __restrict__ btot, int E, int B) {
    __shared__ int cnt[256];
    int tid = threadIdx.x;
    cnt[tid] = 0;
    __syncthreads();
    int e0 = blockIdx.x * 2048;
#pragma unroll
    for (int j = 0; j < 8; ++j) {
        int e = e0 + j * 256 + tid;
        if (e < E) atomicAdd(&cnt[dst[e] >> 8], 1);
    }
    __syncthreads();
    if (tid < B && cnt[tid] > 0) atomicAdd(&btot[tid], cnt[tid]);
}

__global__ void k_bscan(const int* __restrict__ btot, int* __restrict__ bbase,
                        int* __restrict__ bcur, int* __restrict__ row_ptr, int N, int B) {
    __shared__ int sc[256];
    int tid = threadIdx.x;
    int v = (tid < B) ? btot[tid] : 0;
    sc[tid] = v;
    __syncthreads();
    for (int off = 1; off < 256; off <<= 1) {
        int t = (tid >= off) ? sc[tid - off] : 0;
        __syncthreads();
        sc[tid] += t;
        __syncthreads();
    }
    int excl = sc[tid] - v;
    if (tid < B) { bbase[tid] = excl; bcur[tid] = excl; }
    if (tid == B - 1) { bbase[B] = excl + v; row_ptr[N] = excl + v; }
}

// payload u32 = src | ((dst&255) << 16)
__global__ void k_bscatter(const int* __restrict__ src, const int* __restrict__ dst,
                           int* bcur, unsigned int* __restrict__ ebuf, int E, int B) {
    __shared__ int cnt[256];
    __shared__ int gb[256];
    int tid = threadIdx.x;
    cnt[tid] = 0;
    __syncthreads();
    int e0 = blockIdx.x * 2048;
    int bk[8], rk[8];
    unsigned int pay[8];
#pragma unroll
    for (int j = 0; j < 8; ++j) {
        int e = e0 + j * 256 + tid;
        if (e < E) {
            int d = dst[e];
            int b = d >> 8;
            bk[j] = b;
            rk[j] = atomicAdd(&cnt[b], 1);
            pay[j] = (unsigned int)src[e] | ((unsigned int)(d & 255) << 16);
        } else {
            bk[j] = -1; rk[j] = 0; pay[j] = 0;
        }
    }
    __syncthreads();
    if (tid < B && cnt[tid] > 0) gb[tid] = atomicAdd(&bcur[tid], cnt[tid]);
    __syncthreads();
#pragma unroll
    for (int j = 0; j < 8; ++j)
        if (bk[j] >= 0) ebuf[gb[bk[j]] + rk[j]] = pay[j];
}

__global__ void k_bfinal(const unsigned int* __restrict__ ebuf, const int* __restrict__ bbase,
                         int* __restrict__ row_ptr, float* __restrict__ dinv,
                         unsigned short* __restrict__ col, int N) {
    __shared__ int cnt[256];
    __shared__ int sc[256];
    __shared__ int cur[256];
    int tid = threadIdx.x;
    int b = blockIdx.x;
    int node0 = b << 8;
    int ebeg = bbase[b], eend = bbase[b + 1];

    cnt[tid] = 0;
    __syncthreads();
    for (int i = ebeg + tid; i < eend; i += 256)
        atomicAdd(&cnt[ebuf[i] >> 16], 1);
    __syncthreads();
    int myc = cnt[tid];
    sc[tid] = myc;
    __syncthreads();
    for (int off = 1; off < 256; off <<= 1) {
        int t = (tid >= off) ? sc[tid - off] : 0;
        __syncthreads();
        sc[tid] += t;
        __syncthreads();
    }
    int excl = sc[tid] - myc;
    cur[tid] = ebeg + excl;
    int node = node0 + tid;
    if (node < N) {
        row_ptr[node] = ebeg + excl;
        dinv[node] = rsqrtf((float)(myc + 1));  // +1 self-loop
    }
    __syncthreads();
    for (int i = ebeg + tid; i < eend; i += 256) {
        unsigned int p = ebuf[i];
        int dl = p >> 16;
        int pos = atomicAdd(&cur[dl], 1);
        col[pos] = (unsigned short)(p & 0xFFFFu);
    }
}

// ================= GEMM (fp16 operands, fdot2, f32 accum) =================
template <int K, int FOUT, bool FP16IN>
__launch_bounds__(256)
__global__ void k_gemm_scale(const void* __restrict__ Xv, const float* __restrict__ W,
                             const float* __restrict__ dinv, half2_t* __restrict__ HS, int N) {
    constexpr int KK = K / 2;                   // half2 per row
    constexpr int XSTR = (K == 128) ? 66 : 36;  // padded row stride (half2)
    __shared__ half2_t xs2[64][XSTR];
    __shared__ half2_t wl2[KK][FOUT];
    int tid = threadIdx.x;
    int row0 = blockIdx.x * 64;

    if constexpr (FP16IN) {
        const _Float16* X = (const _Float16*)Xv;
        constexpr int U = 64 * K / 8;  // 16B units
        for (int u = tid; u < U; u += 256) {
            int row = u / (K / 8), q = u % (K / 8);
            int grow = row0 + row;
            uint4 v = make_uint4(0u, 0u, 0u, 0u);
            if (grow < N) v = *(const uint4*)&X[(size_t)grow * K + q * 8];
            *(uint4*)&xs2[row][q * 4] = v;
        }
    } else {
        const float* X = (const float*)Xv;
        constexpr int U = 64 * K / 4;  // float4 units
        for (int u = tid; u < U; u += 256) {
            int row = u / (K / 4), c = u % (K / 4);
            int grow = row0 + row;
            half2_t h0 = (half2_t)(_Float16)0, h1 = (half2_t)(_Float16)0;
            if (grow < N) {
                float4 v = *(const float4*)&X[(size_t)grow * K + c * 4];
                h0[0] = (_Float16)v.x; h0[1] = (_Float16)v.y;
                h1[0] = (_Float16)v.z; h1[1] = (_Float16)v.w;
            }
            xs2[row][2 * c] = h0;
            xs2[row][2 * c + 1] = h1;
        }
    }
    for (int i = tid; i < KK * FOUT; i += 256) {
        int kk = i / FOUT, f = i % FOUT;
        half2_t h;
        h[0] = (_Float16)W[(2 * kk) * FOUT + f];
        h[1] = (_Float16)W[(2 * kk + 1) * FOUT + f];
        wl2[kk][f] = h;
    }
    __syncthreads();

    int tc = tid & 15, tr = tid >> 4;
    if (4 * tc < FOUT) {
        float acc[4][4] = {};
#pragma unroll 4
        for (int kk = 0; kk < KK; ++kk) {
            half2_t a0 = xs2[4 * tr + 0][kk];
            half2_t a1 = xs2[4 * tr + 1][kk];
            half2_t a2 = xs2[4 * tr + 2][kk];
            half2_t a3 = xs2[4 * tr + 3][kk];
            half8_t wv = *(const half8_t*)&wl2[kk][4 * tc];
            half2_t w0 = {wv[0], wv[1]};
            half2_t w1 = {wv[2], wv[3]};
            half2_t w2 = {wv[4], wv[5]};
            half2_t w3 = {wv[6], wv[7]};
            acc[0][0] = fdot2(a0, w0, acc[0][0]); acc[0][1] = fdot2(a0, w1, acc[0][1]);
            acc[0][2] = fdot2(a0, w2, acc[0][2]); acc[0][3] = fdot2(a0, w3, acc[0][3]);
            acc[1][0] = fdot2(a1, w0, acc[1][0]); acc[1][1] = fdot2(a1, w1, acc[1][1]);
            acc[1][2] = fdot2(a1, w2, acc[1][2]); acc[1][3] = fdot2(a1, w3, acc[1][3]);
            acc[2][0] = fdot2(a2, w0, acc[2][0]); acc[2][1] = fdot2(a2, w1, acc[2][1]);
            acc[2][2] = fdot2(a2, w2, acc[2][2]); acc[2][3] = fdot2(a2, w3, acc[2][3]);
            acc[3][0] = fdot2(a3, w0, acc[3][0]); acc[3][1] = fdot2(a3, w1, acc[3][1]);
            acc[3][2] = fdot2(a3, w2, acc[3][2]); acc[3][3] = fdot2(a3, w3, acc[3][3]);
        }
#pragma unroll
        for (int i = 0; i < 4; ++i) {
            int row = row0 + 4 * tr + i;
            if (row < N) {
                float dv = dinv[row];
                half2_t p0, p1;
                p0[0] = (_Float16)(dv * acc[i][0]); p0[1] = (_Float16)(dv * acc[i][1]);
                p1[0] = (_Float16)(dv * acc[i][2]); p1[1] = (_Float16)(dv * acc[i][3]);
                HS[(size_t)row * (FOUT / 2) + 2 * tc] = p0;
                HS[(size_t)row * (FOUT / 2) + 2 * tc + 1] = p1;
            }
        }
    }
}

// ================= Aggregation (wide-gather) =================
// wave per node; lane = (group g=lane>>3, sublane s=lane&7).
// Each group processes one edge; lane loads half8 (16B) = features [8s,8s+8).
// 8 edges in flight per wave, x2 unroll. Cross-group reduce: shfl_xor 8/16/32.
template <int FOUT, bool BN>
__launch_bounds__(256)
__global__ void k_agg(const half8_t* __restrict__ hs8, const unsigned short* __restrict__ col,
                      const int* __restrict__ row_ptr, const float* __restrict__ dinv,
                      const float* __restrict__ b, const float* __restrict__ g,
                      const float* __restrict__ be, const float* __restrict__ m,
                      const float* __restrict__ v, void* __restrict__ outv, int N) {
    constexpr int NS = FOUT / 8;  // half8 per row (8 for 64, 5 for 40)
    int gtid = blockIdx.x * blockDim.x + threadIdx.x;
    int wave = gtid >> 6;
    int lane = gtid & 63;
    int g8 = lane >> 3;
    int s = lane & 7;
    int nwaves = (gridDim.x * blockDim.x) >> 6;
    bool act = s < NS;

    float bias[8], sf[8], tf[8];
    if (act) {
#pragma unroll
        for (int j = 0; j < 8; ++j) {
            int f = 8 * s + j;
            bias[j] = b[f];
            if (BN) {
                sf[j] = g[f] * rsqrtf(v[f] + BN_EPS);
                tf[j] = be[f] - m[f] * sf[j];
            }
        }
    }

    for (int node = wave; node < N; node += nwaves) {
        int beg = row_ptr[node], end = row_ptr[node + 1];
        float acc0[8] = {}, acc1[8] = {};
        if (act && g8 == 0) {
            half8_t t = hs8[(size_t)node * NS + s];
#pragma unroll
            for (int j = 0; j < 8; ++j) acc0[j] = (float)t[j];
        }
        int e = beg + g8;
        for (; e + 8 < end; e += 16) {
            int i0 = col[e];
            int i1 = col[e + 8];
            if (act) {
                half8_t t0 = hs8[(size_t)i0 * NS + s];
                half8_t t1 = hs8[(size_t)i1 * NS + s];
#pragma unroll
                for (int j = 0; j < 8; ++j) { acc0[j] += (float)t0[j]; acc1[j] += (float)t1[j]; }
            }
        }
        if (e < end) {
            int i0 = col[e];
            if (act) {
                half8_t t0 = hs8[(size_t)i0 * NS + s];
#pragma unroll
                for (int j = 0; j < 8; ++j) acc0[j] += (float)t0[j];
            }
        }
#pragma unroll
        for (int j = 0; j < 8; ++j) {
            float sj = acc0[j] + acc1[j];
            sj += __shfl_xor(sj, 8);
            sj += __shfl_xor(sj, 16);
            sj += __shfl_xor(sj, 32);
            acc0[j] = sj;
        }
        if (g8 == 0 && act) {
            float dv = dinv[node];
            if (BN) {
                half8_t h;
#pragma unroll
                for (int j = 0; j < 8; ++j) {
                    float o = dv * acc0[j] + bias[j];
                    o = fmaxf(o * sf[j] + tf[j], 0.0f);
                    h[j] = (_Float16)o;
                }
                ((half8_t*)outv)[(size_t)node * NS + s] = h;
            } else {
                float o[8];
#pragma unroll
                for (int j = 0; j < 8; ++j) o[j] = dv * acc0[j] + bias[j];
                float* op = (float*)outv + (size_t)node * FOUT + 8 * s;
                *(float4*)op = make_float4(o[0], o[1], o[2], o[3]);
                *(float4*)(op + 4) = make_float4(o[4], o[5], o[6], o[7]);
            }
        }
    }
}

// ================= launch =================

extern "C" void kernel_launch(void* const* d_in, const int* in_sizes, int n_in,
                              void* d_out, int out_size, void* d_ws, size_t ws_size,
                              hipStream_t stream) {
    const float* x   = (const float*)d_in[0];
    const int*   ei  = (const int*)d_in[1];
    const float* W1  = (const float*)d_in[2];
    const float* b1  = (const float*)d_in[3];
    const float* g1  = (const float*)d_in[4];
    const float* be1 = (const float*)d_in[5];
    const float* m1  = (const float*)d_in[6];
    const float* v1  = (const float*)d_in[7];
    const float* W2  = (const float*)d_in[8];
    const float* b2  = (const float*)d_in[9];
    const float* g2  = (const float*)d_in[10];
    const float* be2 = (const float*)d_in[11];
    const float* m2  = (const float*)d_in[12];
    const float* v2  = (const float*)d_in[13];
    const float* W3  = (const float*)d_in[14];
    const float* b3  = (const float*)d_in[15];

    const int FIN = 128, H = 64;
    int N = in_sizes[0] / FIN;       // 50000
    int E = in_sizes[1] / 2;         // 1600000
    const int* src = ei;
    const int* dst = ei + E;
    int B = (N + 255) >> 8;          // 196 buckets

    char* ws = (char*)d_ws;
    size_t off = 0;
    auto carve = [&](size_t bytes) -> void* {
        void* p = ws + off;
        off += (bytes + 255) & ~(size_t)255;
        return p;
    };
    float*  dinv    = (float*)carve((size_t)N * 4);
    int*    row_ptr = (int*)carve((size_t)(N + 1) * 4);
    unsigned short* col = (unsigned short*)carve((size_t)E * 2);
    unsigned int*   ebuf = (unsigned int*)carve((size_t)E * 4);
    half2_t* hs     = (half2_t*)carve((size_t)N * H * 2);
    _Float16* y     = (_Float16*)carve((size_t)N * H * 2);
    int*    btot    = (int*)carve(512 * 4);
    int*    bbase   = (int*)carve(512 * 4);
    int*    bcur    = (int*)carve(512 * 4);
    (void)ws_size; (void)n_in; (void)out_size;

    int eb2k = (E + 2047) / 2048;

    k_zero<<<1, 256, 0, stream>>>(btot, B);
    k_bcount<<<eb2k, 256, 0, stream>>>(dst, btot, E, B);
    k_bscan<<<1, 256, 0, stream>>>(btot, bbase, bcur, row_ptr, N, B);
    k_bscatter<<<eb2k, 256, 0, stream>>>(src, dst, bcur, ebuf, E, B);
    k_bfinal<<<B, 256, 0, stream>>>(ebuf, bbase, row_ptr, dinv, col, N);

    int gb = (N + 63) / 64;
    const half8_t* hs8 = (const half8_t*)hs;
    // layer 1
    k_gemm_scale<128, 64, false><<<gb, 256, 0, stream>>>(x, W1, dinv, hs, N);
    k_agg<64, true><<<4096, 256, 0, stream>>>(hs8, col, row_ptr, dinv, b1, g1, be1, m1, v1, y, N);
    // layer 2
    k_gemm_scale<64, 64, true><<<gb, 256, 0, stream>>>(y, W2, dinv, hs, N);
    k_agg<64, true><<<4096, 256, 0, stream>>>(hs8, col, row_ptr, dinv, b2, g2, be2, m2, v2, y, N);
    // layer 3
    k_gemm_scale<64, 40, true><<<gb, 256, 0, stream>>>(y, W3, dinv, hs, N);
    k_agg<40, false><<<4096, 256, 0, stream>>>(hs8, col, row_ptr, dinv, b3, nullptr, nullptr, nullptr, nullptr,
                                               d_out, N);
}